// Round 4
// baseline (205.881 us; speedup 1.0000x reference)
//
#include <hip/hip_runtime.h>
#include <hip/hip_bf16.h>

typedef __bf16 bf16x8 __attribute__((ext_vector_type(8)));
typedef float f32x4 __attribute__((ext_vector_type(4)));
typedef float f32x4u __attribute__((ext_vector_type(4), aligned(4)));
typedef unsigned short u16x8 __attribute__((ext_vector_type(8)));

typedef __attribute__((address_space(1))) const unsigned int gu32;
typedef __attribute__((address_space(3))) unsigned int lu32;

#define B_SZ   1024
#define IN_SZ  512
#define HID    128
#define OUT_SZ 64
#define BK     32
#define NKT    16        // K main loop = 512; j=512 handled as rank-1 tail

static __device__ __forceinline__ unsigned short f2bf(float f) {
    __hip_bfloat16 h = __float2bfloat16(f);
    return *reinterpret_cast<unsigned short*>(&h);
}

// ---------------- prep: t_hat bf16, tc, x_hatT ----------------
__global__ __launch_bounds__(256) void prep_kernel(
    const float* __restrict__ img, const float* __restrict__ tab,
    unsigned short* __restrict__ tbt, float* __restrict__ xhT,
    float* __restrict__ tc)
{
    const int blk = blockIdx.x;   // 0..1023
    for (int j = threadIdx.x; j < 512; j += 256) {
        float v = (j == 0) ? 1.0f : tab[(size_t)blk * IN_SZ + (j - 1)];
        tbt[(size_t)blk * 512 + j] = f2bf(v);
    }
    if (threadIdx.x == 0) tc[blk] = tab[(size_t)blk * IN_SZ + 511];
    if (blk < 513) {
        for (int b = threadIdx.x; b < B_SZ; b += 256)
            xhT[(size_t)blk * B_SZ + b] =
                (blk == 0) ? 1.0f : img[(size_t)b * IN_SZ + (blk - 1)];
    }
}

// ---------------- prep2: W1 fp32 [65664][513] -> bf16 [65664][512] ----------
__global__ __launch_bounds__(256) void prep2_kernel(
    const float* __restrict__ w1, unsigned short* __restrict__ w1b)
{
    const long long gid = (long long)blockIdx.x * 256 + threadIdx.x; // 0..65664*64-1
    const int r  = (int)(gid >> 6);
    const int c8 = ((int)gid & 63) << 3;
    const float* src = w1 + (size_t)r * 513 + c8;
    const f32x4u lo = *reinterpret_cast<const f32x4u*>(src);
    const f32x4u hi = *reinterpret_cast<const f32x4u*>(src + 4);
    u16x8 u;
    u[0] = f2bf(lo[0]); u[1] = f2bf(lo[1]); u[2] = f2bf(lo[2]); u[3] = f2bf(lo[3]);
    u[4] = f2bf(hi[0]); u[5] = f2bf(hi[1]); u[6] = f2bf(hi[2]); u[7] = f2bf(hi[3]);
    *reinterpret_cast<u16x8*>(w1b + (size_t)r * 512 + c8) = u;
}

// ---------------- main fused GEMM (bf16 W1 path) ----------------
// BM=128, BN=256, BK=32. 8 waves, wave-grid 2M x 4N, wave-tile 64x64.
__global__ __launch_bounds__(512, 4) void gemm_fused(
    const float* __restrict__ w1, const unsigned short* __restrict__ w1b,
    const unsigned short* __restrict__ tbt,
    const float* __restrict__ xhT, const float* __restrict__ tc,
    float* __restrict__ y1acc)
{
    __shared__ unsigned short Als[2][128 * BK];   // 2 x 8 KB
    __shared__ unsigned short Bls[2][256 * BK];   // 2 x 16 KB

    const int bm = blockIdx.x >> 2;       // 0..512
    const int bn = blockIdx.x & 3;        // 0..3
    const int m0 = bm * 128;
    const int n0 = bn * 256;
    const int tid  = threadIdx.x;
    const int wv   = tid >> 6;
    const int wr   = wv >> 2;             // 0..1
    const int wc   = wv & 3;              // 0..3
    const int lane = tid & 63;
    const int l15  = lane & 15;
    const int kg   = lane >> 4;

    // A staging: phys chunk p = tid (128 rows x 4 chunks), source pre-swizzled
    const unsigned short* asrc;
    {
        const int r  = tid >> 2;
        const int cl = (tid & 3) ^ ((r >> 1) & 3);
        asrc = w1b + (size_t)(m0 + r) * 512 + cl * 8;
    }
    const int aBase = (wv * 64) * 8;

    // B staging: phys chunks p = tid, 512+tid (256 rows x 4 chunks)
    const unsigned short* bsrc[2];
    int bBase[2];
    #pragma unroll
    for (int q = 0; q < 2; ++q) {
        const int p  = q * 512 + tid;
        const int r  = p >> 2;
        const int cl = (p & 3) ^ ((r >> 1) & 3);
        bsrc[q] = tbt + (size_t)(n0 + r) * 512 + cl * 8;
        bBase[q] = (q * 512 + wv * 64) * 8;
    }

    // fragment read offsets (u16 units); phys chunk = kg ^ ((r>>1)&3)
    int aoffs[4], boffs[4];
    #pragma unroll
    for (int ms = 0; ms < 4; ++ms) {
        const int r = wr * 64 + ms * 16 + l15;
        aoffs[ms] = (r * 4 + (kg ^ ((r >> 1) & 3))) * 8;
    }
    #pragma unroll
    for (int ns = 0; ns < 4; ++ns) {
        const int r = wc * 64 + ns * 16 + l15;
        boffs[ns] = (r * 4 + (kg ^ ((r >> 1) & 3))) * 8;
    }

    f32x4 acc[4][4] = {};

#define STAGE(BUF, KT) do {                                                  \
        const int k32_ = (KT) * BK;                                          \
        __builtin_amdgcn_global_load_lds(                                    \
            (gu32*)(const void*)(asrc + k32_),                               \
            (lu32*)(void*)&Als[BUF][aBase], 16, 0, 0);                       \
        _Pragma("unroll")                                                    \
        for (int q_ = 0; q_ < 2; ++q_)                                       \
            __builtin_amdgcn_global_load_lds(                                \
                (gu32*)(const void*)(bsrc[q_] + k32_),                       \
                (lu32*)(void*)&Bls[BUF][bBase[q_]], 16, 0, 0);               \
    } while (0)

    STAGE(0, 0);
    __syncthreads();

    for (int kt = 0; kt < NKT; ++kt) {
        const int cur = kt & 1;
        if (kt + 1 < NKT) STAGE(cur ^ 1, kt + 1);

        const unsigned short* ab = &Als[cur][0];
        const unsigned short* bb = &Bls[cur][0];
        bf16x8 af[4], bfr[4];
        #pragma unroll
        for (int ms = 0; ms < 4; ++ms)
            af[ms] = *reinterpret_cast<const bf16x8*>(&ab[aoffs[ms]]);
        #pragma unroll
        for (int ns = 0; ns < 4; ++ns)
            bfr[ns] = *reinterpret_cast<const bf16x8*>(&bb[boffs[ns]]);
        #pragma unroll
        for (int ms = 0; ms < 4; ++ms)
            #pragma unroll
            for (int ns = 0; ns < 4; ++ns)
                acc[ms][ns] = __builtin_amdgcn_mfma_f32_16x16x32_bf16(
                    af[ms], bfr[ns], acc[ms][ns], 0, 0, 0);
        __syncthreads();
    }
#undef STAGE

    // epilogue: + j=512 rank-1 term (fp32), reduce over i, atomics
    const int h0 = m0 / 513;
    const int mb = (h0 + 1) * 513;
    const bool cross = (mb < m0 + 128);

    float wcv[4][4];
    #pragma unroll
    for (int ms = 0; ms < 4; ++ms)
        #pragma unroll
        for (int v = 0; v < 4; ++v)
            wcv[ms][v] = w1[(size_t)(m0 + wr * 64 + ms * 16 + kg * 4 + v) * 513 + 512];

    #pragma unroll
    for (int ns = 0; ns < 4; ++ns) {
        const int ncol = n0 + wc * 64 + ns * 16 + l15;
        const float tv = tc[ncol];
        float s0 = 0.f, s1 = 0.f;
        #pragma unroll
        for (int ms = 0; ms < 4; ++ms) {
            #pragma unroll
            for (int v = 0; v < 4; ++v) {
                const int m = m0 + wr * 64 + ms * 16 + kg * 4 + v;
                const bool lo = (m < mb);
                const int i = lo ? (m - h0 * 513) : (m - mb);
                const float xv = xhT[(size_t)i * B_SZ + ncol];
                const float val = (acc[ms][ns][v] + wcv[ms][v] * tv) * xv;
                if (lo) s0 += val; else s1 += val;
            }
        }
        s0 += __shfl_xor(s0, 16); s0 += __shfl_xor(s0, 32);
        if (lane < 16) atomicAdd(&y1acc[(size_t)ncol * HID + h0], s0);
        if (cross) {
            s1 += __shfl_xor(s1, 16); s1 += __shfl_xor(s1, 32);
            if (lane < 16 && (h0 + 1) < HID)
                atomicAdd(&y1acc[(size_t)ncol * HID + h0 + 1], s1);
        }
    }
}

// ---------------- fallback GEMM (R3 verbatim, fp32-A path) ----------------
__global__ __launch_bounds__(512, 4) void gemm_fused_fb(
    const float* __restrict__ w1, const unsigned short* __restrict__ tbt,
    const float* __restrict__ xhT, const float* __restrict__ tc,
    float* __restrict__ y1acc)
{
    __shared__ float          Afs[2][64 * BK];
    __shared__ unsigned short Bls[2][512 * BK];

    const int bm = blockIdx.x >> 1;
    const int bn = blockIdx.x & 1;
    const int m0 = bm * 64;
    const int n0 = bn * 512;
    const int tid  = threadIdx.x;
    const int wv   = tid >> 6;
    const int lane = tid & 63;
    const int l15  = lane & 15;
    const int kg   = lane >> 4;

    const int ar  = tid >> 3;
    const int acl = (tid & 7) ^ (ar & 7);
    const float* asrc = w1 + (size_t)(m0 + ar) * 513 + acl * 4;
    const int aBase = (wv * 64) * 4;

    const unsigned short* bsrc[4];
    int bBase[4];
    #pragma unroll
    for (int q = 0; q < 4; ++q) {
        const int p  = q * 512 + tid;
        const int r  = p >> 2;
        const int cl = (p & 3) ^ ((r >> 1) & 3);
        bsrc[q] = tbt + (size_t)(n0 + r) * 512 + cl * 8;
        bBase[q] = (q * 512 + wv * 64) * 8;
    }

    int aoff0[4], aoff1[4], boffs[4];
    #pragma unroll
    for (int ms = 0; ms < 4; ++ms) {
        const int r = ms * 16 + l15;
        aoff0[ms] = r * 32 + (((kg * 2) + 0) ^ (r & 7)) * 4;
        aoff1[ms] = r * 32 + (((kg * 2) + 1) ^ (r & 7)) * 4;
    }
    #pragma unroll
    for (int ns = 0; ns < 4; ++ns) {
        const int r = wv * 64 + ns * 16 + l15;
        boffs[ns] = ((r << 2) | (kg ^ ((r >> 1) & 3))) * 8;
    }

    f32x4 acc[4][4] = {};

#define STAGE_FB(BUF, KT) do {                                               \
        const int k32_ = (KT) * BK;                                          \
        _Pragma("unroll")                                                    \
        for (int q_ = 0; q_ < 4; ++q_)                                       \
            __builtin_amdgcn_global_load_lds(                                \
                (gu32*)(const void*)(bsrc[q_] + k32_),                       \
                (lu32*)(void*)&Bls[BUF][bBase[q_]], 16, 0, 0);               \
        __builtin_amdgcn_global_load_lds(                                    \
            (gu32*)(const void*)(asrc + k32_),                               \
            (lu32*)(void*)&Afs[BUF][aBase], 16, 0, 0);                       \
    } while (0)

    STAGE_FB(0, 0);
    __syncthreads();

    for (int kt = 0; kt < NKT; ++kt) {
        const int cur = kt & 1;
        if (kt + 1 < NKT) STAGE_FB(cur ^ 1, kt + 1);

        const float*          ab = &Afs[cur][0];
        const unsigned short* bb = &Bls[cur][0];
        bf16x8 bfr[4];
        #pragma unroll
        for (int ns = 0; ns < 4; ++ns)
            bfr[ns] = *reinterpret_cast<const bf16x8*>(&bb[boffs[ns]]);
        #pragma unroll
        for (int ms = 0; ms < 4; ++ms) {
            const f32x4 lo = *reinterpret_cast<const f32x4*>(&ab[aoff0[ms]]);
            const f32x4 hi = *reinterpret_cast<const f32x4*>(&ab[aoff1[ms]]);
            u16x8 u;
            u[0] = f2bf(lo[0]); u[1] = f2bf(lo[1]);
            u[2] = f2bf(lo[2]); u[3] = f2bf(lo[3]);
            u[4] = f2bf(hi[0]); u[5] = f2bf(hi[1]);
            u[6] = f2bf(hi[2]); u[7] = f2bf(hi[3]);
            const bf16x8 af = __builtin_bit_cast(bf16x8, u);
            #pragma unroll
            for (int ns = 0; ns < 4; ++ns)
                acc[ms][ns] = __builtin_amdgcn_mfma_f32_16x16x32_bf16(
                    af, bfr[ns], acc[ms][ns], 0, 0, 0);
        }
        __syncthreads();
    }
#undef STAGE_FB

    const int h0 = m0 / 513;
    const int mb = (h0 + 1) * 513;
    const bool cross = (mb < m0 + 64);

    float wcv[4][4];
    #pragma unroll
    for (int ms = 0; ms < 4; ++ms)
        #pragma unroll
        for (int v = 0; v < 4; ++v)
            wcv[ms][v] = w1[(size_t)(m0 + ms * 16 + kg * 4 + v) * 513 + 512];

    #pragma unroll
    for (int ns = 0; ns < 4; ++ns) {
        const int ncol = n0 + wv * 64 + ns * 16 + l15;
        const float tv = tc[ncol];
        float s0 = 0.f, s1 = 0.f;
        #pragma unroll
        for (int ms = 0; ms < 4; ++ms) {
            #pragma unroll
            for (int v = 0; v < 4; ++v) {
                const int m = m0 + ms * 16 + kg * 4 + v;
                const bool lo = (m < mb);
                const int i = lo ? (m - h0 * 513) : (m - mb);
                const float xv = xhT[(size_t)i * B_SZ + ncol];
                const float val = (acc[ms][ns][v] + wcv[ms][v] * tv) * xv;
                if (lo) s0 += val; else s1 += val;
            }
        }
        s0 += __shfl_xor(s0, 16); s0 += __shfl_xor(s0, 32);
        if (lane < 16) atomicAdd(&y1acc[(size_t)ncol * HID + h0], s0);
        if (cross) {
            s1 += __shfl_xor(s1, 16); s1 += __shfl_xor(s1, 32);
            if (lane < 16 && (h0 + 1) < HID)
                atomicAdd(&y1acc[(size_t)ncol * HID + h0 + 1], s1);
        }
    }
}

// ---------------- MLP tail ----------------
__global__ __launch_bounds__(128) void mlp_kernel(
    const float* __restrict__ y1acc, const float* __restrict__ b1,
    const float* __restrict__ W2, const float* __restrict__ b2,
    const float* __restrict__ W3, const float* __restrict__ b3,
    float* __restrict__ out)
{
    __shared__ float y1r[HID];
    __shared__ float y2r[HID];
    const int b = blockIdx.x;
    const int h = threadIdx.x;
    y1r[h] = y1acc[(size_t)b * HID + h] + b1[h];
    __syncthreads();
    float a = b2[h];
    const float* w2r = W2 + (size_t)h * HID;
    #pragma unroll 8
    for (int k = 0; k < HID; ++k) a += w2r[k] * y1r[k];
    y2r[h] = tanhf(a);
    __syncthreads();
    if (h < OUT_SZ) {
        float a3 = b3[h];
        const float* w3r = W3 + (size_t)h * HID;
        #pragma unroll 8
        for (int k = 0; k < HID; ++k) a3 += w3r[k] * y2r[k];
        out[(size_t)b * OUT_SZ + h] = fmaxf(a3, 0.f);
    }
}

extern "C" void kernel_launch(void* const* d_in, const int* in_sizes, int n_in,
                              void* d_out, int out_size, void* d_ws, size_t ws_size,
                              hipStream_t stream) {
    const float* img = (const float*)d_in[0];
    const float* tab = (const float*)d_in[1];
    const float* W1  = (const float*)d_in[2];
    const float* b1  = (const float*)d_in[3];
    const float* W2  = (const float*)d_in[4];
    const float* b2  = (const float*)d_in[5];
    const float* W3  = (const float*)d_in[6];
    const float* b3  = (const float*)d_in[7];
    float* out = (float*)d_out;

    char* ws = (char*)d_ws;
    float*          y1acc = (float*)ws;                        // 524288 B
    unsigned short* tbt   = (unsigned short*)(ws + 524288);    // 1048576 B
    float*          xhT   = (float*)(ws + 1572864);            // 2101248 B
    float*          tc    = (float*)(ws + 3674112);            // 4096 B
    unsigned short* w1b   = (unsigned short*)(ws + 3678208);   // 67239936 B
    const size_t need = 3678208ULL + 67239936ULL;

    hipMemsetAsync(y1acc, 0, (size_t)B_SZ * HID * sizeof(float), stream);
    prep_kernel<<<dim3(1024), dim3(256), 0, stream>>>(img, tab, tbt, xhT, tc);
    if (ws_size >= need) {
        prep2_kernel<<<dim3(65664 * 64 / 256), dim3(256), 0, stream>>>(W1, w1b);
        gemm_fused<<<dim3(2052), dim3(512), 0, stream>>>(W1, w1b, tbt, xhT, tc, y1acc);
    } else {
        gemm_fused_fb<<<dim3(2052), dim3(512), 0, stream>>>(W1, tbt, xhT, tc, y1acc);
    }
    mlp_kernel<<<dim3(1024), dim3(128), 0, stream>>>(y1acc, b1, W2, b2, W3, b3, out);
}

// Round 5
// 188.251 us; speedup vs baseline: 1.0937x; 1.0937x over previous
//
#include <hip/hip_runtime.h>
#include <hip/hip_bf16.h>

typedef __bf16 bf16x8 __attribute__((ext_vector_type(8)));
typedef float f32x4 __attribute__((ext_vector_type(4)));
typedef float f32x4u __attribute__((ext_vector_type(4), aligned(4)));
typedef unsigned short u16x8 __attribute__((ext_vector_type(8)));

typedef __attribute__((address_space(1))) const unsigned int gu32;
typedef __attribute__((address_space(3))) unsigned int lu32;

#define B_SZ   1024
#define IN_SZ  512
#define HID    128
#define OUT_SZ 64
#define BK     32
#define NKT    16        // K main loop = 512; j=512 handled as rank-1 tail

static __device__ __forceinline__ unsigned short f2bf(float f) {
    __hip_bfloat16 h = __float2bfloat16(f);
    return *reinterpret_cast<unsigned short*>(&h);
}

// ---------------- prep: t_hat bf16, tc, x_hatT ----------------
__global__ __launch_bounds__(256) void prep_kernel(
    const float* __restrict__ img, const float* __restrict__ tab,
    unsigned short* __restrict__ tbt, float* __restrict__ xhT,
    float* __restrict__ tc)
{
    const int blk = blockIdx.x;   // 0..1023
    for (int j = threadIdx.x; j < 512; j += 256) {
        float v = (j == 0) ? 1.0f : tab[(size_t)blk * IN_SZ + (j - 1)];
        tbt[(size_t)blk * 512 + j] = f2bf(v);
    }
    if (threadIdx.x == 0) tc[blk] = tab[(size_t)blk * IN_SZ + 511];
    if (blk < 513) {
        for (int b = threadIdx.x; b < B_SZ; b += 256)
            xhT[(size_t)blk * B_SZ + b] =
                (blk == 0) ? 1.0f : img[(size_t)b * IN_SZ + (blk - 1)];
    }
}

// ---------------- prep2: W1 fp32 [65664][513] -> bf16 [65664][512] ----------
__global__ __launch_bounds__(256) void prep2_kernel(
    const float* __restrict__ w1, unsigned short* __restrict__ w1b)
{
    const long long gid = (long long)blockIdx.x * 256 + threadIdx.x; // 0..65664*64-1
    const int r  = (int)(gid >> 6);
    const int c8 = ((int)gid & 63) << 3;
    const float* src = w1 + (size_t)r * 513 + c8;
    const f32x4u lo = *reinterpret_cast<const f32x4u*>(src);
    const f32x4u hi = *reinterpret_cast<const f32x4u*>(src + 4);
    u16x8 u;
    u[0] = f2bf(lo[0]); u[1] = f2bf(lo[1]); u[2] = f2bf(lo[2]); u[3] = f2bf(lo[3]);
    u[4] = f2bf(hi[0]); u[5] = f2bf(hi[1]); u[6] = f2bf(hi[2]); u[7] = f2bf(hi[3]);
    *reinterpret_cast<u16x8*>(w1b + (size_t)r * 512 + c8) = u;
}

// ---------------- main fused GEMM (bf16 W1, 3-buf counted-vmcnt) ----------
// BM=128, BN=256, BK=32. 8 waves, wave-grid 2M x 4N, wave-tile 64x64.
__global__ __launch_bounds__(512, 4) void gemm_fused(
    const float* __restrict__ w1, const unsigned short* __restrict__ w1b,
    const unsigned short* __restrict__ tbt,
    const float* __restrict__ xhT, const float* __restrict__ tc,
    float* __restrict__ y1acc)
{
    __shared__ unsigned short Als[3][128 * BK];   // 3 x 8 KB
    __shared__ unsigned short Bls[3][256 * BK];   // 3 x 16 KB

    // T1: bijective XCD-chunked swizzle (nwg=2052, 8 XCDs; q=256, r=4)
    int wgid;
    {
        const int orig = blockIdx.x;
        const int xcd = orig & 7;
        const int pos = orig >> 3;
        wgid = (xcd < 4 ? xcd * 257 : 4 * 257 + (xcd - 4) * 256) + pos;
    }
    const int bm = wgid >> 2;             // 0..512
    const int bn = wgid & 3;              // 0..3
    const int m0 = bm * 128;
    const int n0 = bn * 256;
    const int tid  = threadIdx.x;
    const int wv   = tid >> 6;
    const int wr   = wv >> 2;             // 0..1
    const int wc   = wv & 3;              // 0..3
    const int lane = tid & 63;
    const int l15  = lane & 15;
    const int kg   = lane >> 4;

    // A staging: phys chunk p = tid (128 rows x 4 chunks), source pre-swizzled
    const unsigned short* asrc;
    {
        const int r  = tid >> 2;
        const int cl = (tid & 3) ^ ((r >> 1) & 3);
        asrc = w1b + (size_t)(m0 + r) * 512 + cl * 8;
    }
    const int aBase = (wv * 64) * 8;

    // B staging: phys chunks p = tid, 512+tid (256 rows x 4 chunks)
    const unsigned short* bsrc[2];
    int bBase[2];
    #pragma unroll
    for (int q = 0; q < 2; ++q) {
        const int p  = q * 512 + tid;
        const int r  = p >> 2;
        const int cl = (p & 3) ^ ((r >> 1) & 3);
        bsrc[q] = tbt + (size_t)(n0 + r) * 512 + cl * 8;
        bBase[q] = (q * 512 + wv * 64) * 8;
    }

    // fragment read offsets (u16 units); phys chunk = kg ^ ((r>>1)&3)
    int aoffs[4], boffs[4];
    #pragma unroll
    for (int ms = 0; ms < 4; ++ms) {
        const int r = wr * 64 + ms * 16 + l15;
        aoffs[ms] = (r * 4 + (kg ^ ((r >> 1) & 3))) * 8;
    }
    #pragma unroll
    for (int ns = 0; ns < 4; ++ns) {
        const int r = wc * 64 + ns * 16 + l15;
        boffs[ns] = (r * 4 + (kg ^ ((r >> 1) & 3))) * 8;
    }

    f32x4 acc[4][4] = {};

#define STAGE(BUF, KT) do {                                                  \
        const int k32_ = (KT) * BK;                                          \
        __builtin_amdgcn_global_load_lds(                                    \
            (gu32*)(const void*)(asrc + k32_),                               \
            (lu32*)(void*)&Als[BUF][aBase], 16, 0, 0);                       \
        _Pragma("unroll")                                                    \
        for (int q_ = 0; q_ < 2; ++q_)                                       \
            __builtin_amdgcn_global_load_lds(                                \
                (gu32*)(const void*)(bsrc[q_] + k32_),                       \
                (lu32*)(void*)&Bls[BUF][bBase[q_]], 16, 0, 0);               \
    } while (0)

    STAGE(0, 0);
    STAGE(1, 1);

    #pragma unroll
    for (int kt = 0; kt < NKT; ++kt) {
        // T4: counted vmcnt — only my oldest stage must have landed; the
        // newest 3 loads stay in flight across the barrier.
        if (kt == NKT - 1) asm volatile("s_waitcnt vmcnt(0)" ::: "memory");
        else               asm volatile("s_waitcnt vmcnt(3)" ::: "memory");
        __builtin_amdgcn_s_barrier();
        __builtin_amdgcn_sched_barrier(0);

        if (kt + 2 < NKT) STAGE((kt + 2) % 3, kt + 2);

        const int cur = kt % 3;
        const unsigned short* ab = &Als[cur][0];
        const unsigned short* bb = &Bls[cur][0];
        bf16x8 af[4], bfr[4];
        #pragma unroll
        for (int ms = 0; ms < 4; ++ms)
            af[ms] = *reinterpret_cast<const bf16x8*>(&ab[aoffs[ms]]);
        #pragma unroll
        for (int ns = 0; ns < 4; ++ns)
            bfr[ns] = *reinterpret_cast<const bf16x8*>(&bb[boffs[ns]]);
        __builtin_amdgcn_s_setprio(1);
        #pragma unroll
        for (int ms = 0; ms < 4; ++ms)
            #pragma unroll
            for (int ns = 0; ns < 4; ++ns)
                acc[ms][ns] = __builtin_amdgcn_mfma_f32_16x16x32_bf16(
                    af[ms], bfr[ns], acc[ms][ns], 0, 0, 0);
        __builtin_amdgcn_s_setprio(0);
    }
#undef STAGE

    // epilogue: + j=512 rank-1 term (fp32), reduce over i, atomics
    const int h0 = m0 / 513;
    const int mb = (h0 + 1) * 513;
    const bool cross = (mb < m0 + 128);

    float wcv[4][4];
    #pragma unroll
    for (int ms = 0; ms < 4; ++ms)
        #pragma unroll
        for (int v = 0; v < 4; ++v)
            wcv[ms][v] = w1[(size_t)(m0 + wr * 64 + ms * 16 + kg * 4 + v) * 513 + 512];

    #pragma unroll
    for (int ns = 0; ns < 4; ++ns) {
        const int ncol = n0 + wc * 64 + ns * 16 + l15;
        const float tv = tc[ncol];
        float s0 = 0.f, s1 = 0.f;
        #pragma unroll
        for (int ms = 0; ms < 4; ++ms) {
            #pragma unroll
            for (int v = 0; v < 4; ++v) {
                const int m = m0 + wr * 64 + ms * 16 + kg * 4 + v;
                const bool lo = (m < mb);
                const int i = lo ? (m - h0 * 513) : (m - mb);
                const float xv = xhT[(size_t)i * B_SZ + ncol];
                const float val = (acc[ms][ns][v] + wcv[ms][v] * tv) * xv;
                if (lo) s0 += val; else s1 += val;
            }
        }
        s0 += __shfl_xor(s0, 16); s0 += __shfl_xor(s0, 32);
        if (lane < 16) atomicAdd(&y1acc[(size_t)ncol * HID + h0], s0);
        if (cross) {
            s1 += __shfl_xor(s1, 16); s1 += __shfl_xor(s1, 32);
            if (lane < 16 && (h0 + 1) < HID)
                atomicAdd(&y1acc[(size_t)ncol * HID + h0 + 1], s1);
        }
    }
}

// ---------------- fallback GEMM (fp32-A path, no prep2 needed) ----------------
__global__ __launch_bounds__(512, 4) void gemm_fused_fb(
    const float* __restrict__ w1, const unsigned short* __restrict__ tbt,
    const float* __restrict__ xhT, const float* __restrict__ tc,
    float* __restrict__ y1acc)
{
    __shared__ float          Afs[2][64 * BK];
    __shared__ unsigned short Bls[2][512 * BK];

    const int bm = blockIdx.x >> 1;
    const int bn = blockIdx.x & 1;
    const int m0 = bm * 64;
    const int n0 = bn * 512;
    const int tid  = threadIdx.x;
    const int wv   = tid >> 6;
    const int lane = tid & 63;
    const int l15  = lane & 15;
    const int kg   = lane >> 4;

    const int ar  = tid >> 3;
    const int acl = (tid & 7) ^ (ar & 7);
    const float* asrc = w1 + (size_t)(m0 + ar) * 513 + acl * 4;
    const int aBase = (wv * 64) * 4;

    const unsigned short* bsrc[4];
    int bBase[4];
    #pragma unroll
    for (int q = 0; q < 4; ++q) {
        const int p  = q * 512 + tid;
        const int r  = p >> 2;
        const int cl = (p & 3) ^ ((r >> 1) & 3);
        bsrc[q] = tbt + (size_t)(n0 + r) * 512 + cl * 8;
        bBase[q] = (q * 512 + wv * 64) * 8;
    }

    int aoff0[4], aoff1[4], boffs[4];
    #pragma unroll
    for (int ms = 0; ms < 4; ++ms) {
        const int r = ms * 16 + l15;
        aoff0[ms] = r * 32 + (((kg * 2) + 0) ^ (r & 7)) * 4;
        aoff1[ms] = r * 32 + (((kg * 2) + 1) ^ (r & 7)) * 4;
    }
    #pragma unroll
    for (int ns = 0; ns < 4; ++ns) {
        const int r = wv * 64 + ns * 16 + l15;
        boffs[ns] = ((r << 2) | (kg ^ ((r >> 1) & 3))) * 8;
    }

    f32x4 acc[4][4] = {};

#define STAGE_FB(BUF, KT) do {                                               \
        const int k32_ = (KT) * BK;                                          \
        _Pragma("unroll")                                                    \
        for (int q_ = 0; q_ < 4; ++q_)                                       \
            __builtin_amdgcn_global_load_lds(                                \
                (gu32*)(const void*)(bsrc[q_] + k32_),                       \
                (lu32*)(void*)&Bls[BUF][bBase[q_]], 16, 0, 0);               \
        __builtin_amdgcn_global_load_lds(                                    \
            (gu32*)(const void*)(asrc + k32_),                               \
            (lu32*)(void*)&Afs[BUF][aBase], 16, 0, 0);                       \
    } while (0)

    STAGE_FB(0, 0);
    __syncthreads();

    for (int kt = 0; kt < NKT; ++kt) {
        const int cur = kt & 1;
        if (kt + 1 < NKT) STAGE_FB(cur ^ 1, kt + 1);

        const float*          ab = &Afs[cur][0];
        const unsigned short* bb = &Bls[cur][0];
        bf16x8 bfr[4];
        #pragma unroll
        for (int ns = 0; ns < 4; ++ns)
            bfr[ns] = *reinterpret_cast<const bf16x8*>(&bb[boffs[ns]]);
        #pragma unroll
        for (int ms = 0; ms < 4; ++ms) {
            const f32x4 lo = *reinterpret_cast<const f32x4*>(&ab[aoff0[ms]]);
            const f32x4 hi = *reinterpret_cast<const f32x4*>(&ab[aoff1[ms]]);
            u16x8 u;
            u[0] = f2bf(lo[0]); u[1] = f2bf(lo[1]);
            u[2] = f2bf(lo[2]); u[3] = f2bf(lo[3]);
            u[4] = f2bf(hi[0]); u[5] = f2bf(hi[1]);
            u[6] = f2bf(hi[2]); u[7] = f2bf(hi[3]);
            const bf16x8 af = __builtin_bit_cast(bf16x8, u);
            #pragma unroll
            for (int ns = 0; ns < 4; ++ns)
                acc[ms][ns] = __builtin_amdgcn_mfma_f32_16x16x32_bf16(
                    af, bfr[ns], acc[ms][ns], 0, 0, 0);
        }
        __syncthreads();
    }
#undef STAGE_FB

    const int h0 = m0 / 513;
    const int mb = (h0 + 1) * 513;
    const bool cross = (mb < m0 + 64);

    float wcv[4][4];
    #pragma unroll
    for (int ms = 0; ms < 4; ++ms)
        #pragma unroll
        for (int v = 0; v < 4; ++v)
            wcv[ms][v] = w1[(size_t)(m0 + ms * 16 + kg * 4 + v) * 513 + 512];

    #pragma unroll
    for (int ns = 0; ns < 4; ++ns) {
        const int ncol = n0 + wv * 64 + ns * 16 + l15;
        const float tv = tc[ncol];
        float s0 = 0.f, s1 = 0.f;
        #pragma unroll
        for (int ms = 0; ms < 4; ++ms) {
            #pragma unroll
            for (int v = 0; v < 4; ++v) {
                const int m = m0 + ms * 16 + kg * 4 + v;
                const bool lo = (m < mb);
                const int i = lo ? (m - h0 * 513) : (m - mb);
                const float xv = xhT[(size_t)i * B_SZ + ncol];
                const float val = (acc[ms][ns][v] + wcv[ms][v] * tv) * xv;
                if (lo) s0 += val; else s1 += val;
            }
        }
        s0 += __shfl_xor(s0, 16); s0 += __shfl_xor(s0, 32);
        if (lane < 16) atomicAdd(&y1acc[(size_t)ncol * HID + h0], s0);
        if (cross) {
            s1 += __shfl_xor(s1, 16); s1 += __shfl_xor(s1, 32);
            if (lane < 16 && (h0 + 1) < HID)
                atomicAdd(&y1acc[(size_t)ncol * HID + h0 + 1], s1);
        }
    }
}

// ---------------- MLP tail ----------------
__global__ __launch_bounds__(128) void mlp_kernel(
    const float* __restrict__ y1acc, const float* __restrict__ b1,
    const float* __restrict__ W2, const float* __restrict__ b2,
    const float* __restrict__ W3, const float* __restrict__ b3,
    float* __restrict__ out)
{
    __shared__ float y1r[HID];
    __shared__ float y2r[HID];
    const int b = blockIdx.x;
    const int h = threadIdx.x;
    y1r[h] = y1acc[(size_t)b * HID + h] + b1[h];
    __syncthreads();
    float a = b2[h];
    const float* w2r = W2 + (size_t)h * HID;
    #pragma unroll 8
    for (int k = 0; k < HID; ++k) a += w2r[k] * y1r[k];
    y2r[h] = tanhf(a);
    __syncthreads();
    if (h < OUT_SZ) {
        float a3 = b3[h];
        const float* w3r = W3 + (size_t)h * HID;
        #pragma unroll 8
        for (int k = 0; k < HID; ++k) a3 += w3r[k] * y2r[k];
        out[(size_t)b * OUT_SZ + h] = fmaxf(a3, 0.f);
    }
}

extern "C" void kernel_launch(void* const* d_in, const int* in_sizes, int n_in,
                              void* d_out, int out_size, void* d_ws, size_t ws_size,
                              hipStream_t stream) {
    const float* img = (const float*)d_in[0];
    const float* tab = (const float*)d_in[1];
    const float* W1  = (const float*)d_in[2];
    const float* b1  = (const float*)d_in[3];
    const float* W2  = (const float*)d_in[4];
    const float* b2  = (const float*)d_in[5];
    const float* W3  = (const float*)d_in[6];
    const float* b3  = (const float*)d_in[7];
    float* out = (float*)d_out;

    char* ws = (char*)d_ws;
    float*          y1acc = (float*)ws;                        // 524288 B
    unsigned short* tbt   = (unsigned short*)(ws + 524288);    // 1048576 B
    float*          xhT   = (float*)(ws + 1572864);            // 2101248 B
    float*          tc    = (float*)(ws + 3674112);            // 4096 B
    unsigned short* w1b   = (unsigned short*)(ws + 3678208);   // 67239936 B
    const size_t need = 3678208ULL + 67239936ULL;

    hipMemsetAsync(y1acc, 0, (size_t)B_SZ * HID * sizeof(float), stream);
    prep_kernel<<<dim3(1024), dim3(256), 0, stream>>>(img, tab, tbt, xhT, tc);
    if (ws_size >= need) {
        prep2_kernel<<<dim3(65664 * 64 / 256), dim3(256), 0, stream>>>(W1, w1b);
        gemm_fused<<<dim3(2052), dim3(512), 0, stream>>>(W1, w1b, tbt, xhT, tc, y1acc);
    } else {
        gemm_fused_fb<<<dim3(2052), dim3(512), 0, stream>>>(W1, tbt, xhT, tc, y1acc);
    }
    mlp_kernel<<<dim3(1024), dim3(128), 0, stream>>>(y1acc, b1, W2, b2, W3, b3, out);
}